// Round 1
// baseline (510.941 us; speedup 1.0000x reference)
//
#include <hip/hip_runtime.h>
#include <stdint.h>

#define SS 768
#define CH 16
#define NCLS 5
#define BN_EPS 1e-4f

static constexpr long long S3LL = (long long)SS * SS * SS;       // 452,984,832
static constexpr size_t BM_BYTES = (size_t)(S3LL / 8) + 64;      // +slack word for 64b window reads

// ---------------- kernel 1: build occupancy bitmap ----------------
__global__ void build_bitmap(const float* __restrict__ pc, uint32_t* __restrict__ bm, int n) {
    int i = blockIdx.x * blockDim.x + threadIdx.x;
    if (i >= n) return;
    int x = (int)pc[i * 5 + 0];
    int y = (int)pc[i * 5 + 1];
    int z = (int)pc[i * 5 + 2];
    uint32_t key = ((uint32_t)x * SS + (uint32_t)y) * SS + (uint32_t)z;
    atomicOr(&bm[key >> 5], 1u << (key & 31));
}

// ---------------- kernel 2: 27-neighbor mask + BN partial stats ----------------
__global__ void mask_stats(const float* __restrict__ pc, const uint32_t* __restrict__ bm,
                           const float* __restrict__ W, uint32_t* __restrict__ masks,
                           float* __restrict__ partials, int n) {
    __shared__ float sW[27 * CH];
    __shared__ float sred[4][32];
    int t = threadIdx.x;
    for (int j = t; j < 27 * CH; j += blockDim.x) sW[j] = W[j];
    __syncthreads();

    int i = blockIdx.x * blockDim.x + t;
    float o[CH];
#pragma unroll
    for (int m = 0; m < CH; m++) o[m] = 0.f;

    if (i < n) {
        int x = (int)pc[i * 5 + 0];
        int y = (int)pc[i * 5 + 1];
        int z = (int)pc[i * 5 + 2];
        uint32_t mask = 0;
        int zlo = (z > 0) ? (z - 1) : 0;
#pragma unroll
        for (int dx = -1; dx <= 1; dx++) {
            int nx = x + dx;
            if (nx < 0 || nx >= SS) continue;
#pragma unroll
            for (int dy = -1; dy <= 1; dy++) {
                int ny = y + dy;
                if (ny < 0 || ny >= SS) continue;
                // 3 consecutive bits (dz=-1,0,+1) in one 64-bit window
                uint32_t base = ((uint32_t)nx * SS + (uint32_t)ny) * SS + (uint32_t)zlo;
                uint32_t wi = base >> 5, sh = base & 31;
                uint64_t dw = (uint64_t)bm[wi] | ((uint64_t)bm[wi + 1] << 32);
                uint32_t three = (uint32_t)(dw >> sh) & 7u;
                if (z == 0)      three = (three << 1) & 7u;  // bit0 (dz=-1) invalid
                if (z == SS - 1) three &= 3u;                // bit2 (dz=+1) wraps, invalid
                int kbase = ((dx + 1) * 3 + (dy + 1)) * 3;
                mask |= three << kbase;
            }
        }
        masks[i] = mask;
        uint32_t mm = mask;
        while (mm) {
            int k = __builtin_ctz(mm);
            mm &= mm - 1;
#pragma unroll
            for (int m = 0; m < CH; m++) o[m] += sW[k * CH + m];
        }
    }

    // wave butterfly reduce (64 lanes) of sum and sumsq per channel
    int lane = t & 63, wid = t >> 6;
#pragma unroll
    for (int m = 0; m < CH; m++) {
        float v = o[m];
        float v2 = o[m] * o[m];
        for (int off = 32; off; off >>= 1) {
            v += __shfl_xor(v, off, 64);
            v2 += __shfl_xor(v2, off, 64);
        }
        if (lane == 0) { sred[wid][m] = v; sred[wid][16 + m] = v2; }
    }
    __syncthreads();
    if (t < 32) {
        float s = 0.f;
        int nw = blockDim.x >> 6;
        for (int w = 0; w < nw; w++) s += sred[w][t];
        partials[(size_t)blockIdx.x * 32 + t] = s;
    }
}

// ---------------- kernel 3: reduce per-block partials (deterministic, fp64 acc) ----------------
__global__ void reduce_stats(const float* __restrict__ partials, float* __restrict__ sums, int nblk) {
    int s = blockIdx.x;  // 0..31: [0,16)=sum, [16,32)=sumsq
    double acc = 0.0;
    for (int i = threadIdx.x; i < nblk; i += blockDim.x)
        acc += (double)partials[(size_t)i * 32 + s];
    __shared__ double sd[256];
    sd[threadIdx.x] = acc;
    __syncthreads();
    for (int h = 128; h; h >>= 1) {
        if (threadIdx.x < h) sd[threadIdx.x] += sd[threadIdx.x + h];
        __syncthreads();
    }
    if (threadIdx.x == 0) sums[s] = (float)sd[0];
}

// ---------------- kernel 4: BN + ReLU + linear epilogue ----------------
__global__ void final_out(const uint32_t* __restrict__ masks, const float* __restrict__ W,
                          const float* __restrict__ sums, const float* __restrict__ gamma,
                          const float* __restrict__ beta, const float* __restrict__ lin_w,
                          const float* __restrict__ lin_b, float* __restrict__ out, int n) {
    __shared__ float sW[27 * CH];
    __shared__ float sA[CH], sB[CH], sLW[CH * NCLS], sLB[NCLS];
    int t = threadIdx.x;
    for (int j = t; j < 27 * CH; j += blockDim.x) sW[j] = W[j];
    if (t < CH) {
        float mean = sums[t] / (float)n;
        float var = sums[16 + t] / (float)n - mean * mean;
        float istd = rsqrtf(var + BN_EPS);
        float a = istd * gamma[t];
        sA[t] = a;
        sB[t] = beta[t] - mean * a;
    }
    if (t < CH * NCLS) sLW[t] = lin_w[t];
    if (t < NCLS) sLB[t] = lin_b[t];
    __syncthreads();

    int i = blockIdx.x * blockDim.x + t;
    if (i >= n) return;
    uint32_t mm = masks[i];
    float o[CH];
#pragma unroll
    for (int m = 0; m < CH; m++) o[m] = 0.f;
    while (mm) {
        int k = __builtin_ctz(mm);
        mm &= mm - 1;
#pragma unroll
        for (int m = 0; m < CH; m++) o[m] += sW[k * CH + m];
    }
    float res[NCLS];
#pragma unroll
    for (int c = 0; c < NCLS; c++) res[c] = sLB[c];
#pragma unroll
    for (int m = 0; m < CH; m++) {
        float h = fmaxf(o[m] * sA[m] + sB[m], 0.f);
#pragma unroll
        for (int c = 0; c < NCLS; c++) res[c] += h * sLW[m * NCLS + c];
    }
#pragma unroll
    for (int c = 0; c < NCLS; c++) out[(size_t)i * NCLS + c] = res[c];
}

extern "C" void kernel_launch(void* const* d_in, const int* in_sizes, int n_in,
                              void* d_out, int out_size, void* d_ws, size_t ws_size,
                              hipStream_t stream) {
    const float* pc    = (const float*)d_in[0];
    const float* W     = (const float*)d_in[1];
    const float* gamma = (const float*)d_in[2];
    const float* beta  = (const float*)d_in[3];
    const float* lin_w = (const float*)d_in[4];
    const float* lin_b = (const float*)d_in[5];
    float* out = (float*)d_out;

    int n = in_sizes[0] / 5;
    int nblk = (n + 255) / 256;

    // workspace layout
    char* ws = (char*)d_ws;
    float* sums = (float*)ws;                                   // 32 floats
    float* partials = (float*)(ws + 256);                       // nblk*32 floats
    size_t off_bm = 256 + (size_t)nblk * 32 * sizeof(float);
    off_bm = (off_bm + 255) & ~(size_t)255;
    uint32_t* bm = (uint32_t*)(ws + off_bm);
    size_t off_masks = off_bm + BM_BYTES;
    uint32_t* masks = (uint32_t*)(ws + off_masks);
    size_t need = off_masks + (size_t)n * sizeof(uint32_t);
    if (ws_size < need) return;  // clean failure (out stays zero) rather than OOB writes

    hipMemsetAsync(bm, 0, BM_BYTES, stream);
    build_bitmap<<<nblk, 256, 0, stream>>>(pc, bm, n);
    mask_stats<<<nblk, 256, 0, stream>>>(pc, bm, W, masks, partials, n);
    reduce_stats<<<32, 256, 0, stream>>>(partials, sums, nblk);
    final_out<<<nblk, 256, 0, stream>>>(masks, W, sums, gamma, beta, lin_w, lin_b, out, n);
}

// Round 2
// 357.283 us; speedup vs baseline: 1.4301x; 1.4301x over previous
//
#include <hip/hip_runtime.h>
#include <stdint.h>

#define SS 768
#define BB 192            // SS/4 : block grid per axis (4x4x4 voxel blocks)
#define CH 16
#define NCLS 5
#define BN_EPS 1e-4f

static constexpr size_t FINE_WORDS   = (size_t)BB * BB * BB;   // 7,077,888 uint64 blocks
static constexpr size_t FINE_BYTES   = FINE_WORDS * 8;         // 56,623,104
static constexpr size_t COARSE_BYTES = FINE_WORDS / 8;         // 884,736 (1 bit per block)

// ---------------- kernel 1: build fine occupancy bitmap (4x4x4 uint64 blocks) ----------------
__global__ void build_fine(const float* __restrict__ pc, unsigned long long* __restrict__ fine, int n) {
    int i = blockIdx.x * blockDim.x + threadIdx.x;
    if (i >= n) return;
    int x = (int)pc[i * 5 + 0];
    int y = (int)pc[i * 5 + 1];
    int z = (int)pc[i * 5 + 2];
    int id = ((x >> 2) * BB + (y >> 2)) * BB + (z >> 2);
    int bit = ((x & 3) * 4 + (y & 3)) * 4 + (z & 3);
    atomicOr(&fine[id], 1ull << bit);
}

// ---------------- kernel 2: coarse map from fine (streaming, ballot) ----------------
__global__ void build_coarse(const unsigned long long* __restrict__ fine,
                             unsigned long long* __restrict__ coarse64) {
    size_t g = (size_t)blockIdx.x * blockDim.x + threadIdx.x;   // grid covers FINE_WORDS exactly
    unsigned long long v = fine[g];
    unsigned long long bal = __ballot(v != 0ull);
    if ((threadIdx.x & 63) == 0) coarse64[g >> 6] = bal;
}

// ---------------- kernel 3: 27-neighbor mask + BN stats (two-level probe) ----------------
__global__ void mask_stats(const float* __restrict__ pc, const unsigned long long* __restrict__ fine,
                           const uint32_t* __restrict__ coarse, const float* __restrict__ W,
                           uint32_t* __restrict__ masks, float* __restrict__ sums, int n) {
    __shared__ float sW[27 * CH];
    __shared__ float sred[4][32];
    int t = threadIdx.x;
    for (int j = t; j < 27 * CH; j += blockDim.x) sW[j] = W[j];
    __syncthreads();

    int i = blockIdx.x * blockDim.x + t;
    float o[CH];
#pragma unroll
    for (int m = 0; m < CH; m++) o[m] = 0.f;

    if (i < n) {
        int x = (int)pc[i * 5 + 0];
        int y = (int)pc[i * 5 + 1];
        int z = (int)pc[i * 5 + 2];

        int bxl = (x > 0 ? x - 1 : 0) >> 2, bxh = (x < SS - 1 ? x + 1 : SS - 1) >> 2;
        int byl = (y > 0 ? y - 1 : 0) >> 2, byh = (y < SS - 1 ? y + 1 : SS - 1) >> 2;
        int bzl = (z > 0 ? z - 1 : 0) >> 2, bzh = (z < SS - 1 ? z + 1 : SS - 1) >> 2;
        bool mx = bxh > bxl, my = byh > byl, mz = bzh > bzl;

        auto loadblk = [&](int bx, int by, int bz) -> unsigned long long {
            int id = (bx * BB + by) * BB + bz;
            uint32_t cb = coarse[id >> 5];
            if (!((cb >> (id & 31)) & 1u)) return 0ull;
            return fine[id];
        };

        unsigned long long b000 = loadblk(bxl, byl, bzl);
        unsigned long long b001 = mz ? loadblk(bxl, byl, bzh) : 0ull;
        unsigned long long b010 = my ? loadblk(bxl, byh, bzl) : 0ull;
        unsigned long long b011 = (my && mz) ? loadblk(bxl, byh, bzh) : 0ull;
        unsigned long long b100 = mx ? loadblk(bxh, byl, bzl) : 0ull;
        unsigned long long b101 = (mx && mz) ? loadblk(bxh, byl, bzh) : 0ull;
        unsigned long long b110 = (mx && my) ? loadblk(bxh, byh, bzl) : 0ull;
        unsigned long long b111 = (mx && my && mz) ? loadblk(bxh, byh, bzh) : 0ull;

        uint32_t mask = 0;
#pragma unroll
        for (int dx = -1; dx <= 1; dx++) {
            int nx = x + dx;
            if ((unsigned)nx >= SS) continue;
            int ix = (nx >> 2) - bxl;
            unsigned long long p00 = ix ? b100 : b000;
            unsigned long long p01 = ix ? b101 : b001;
            unsigned long long p10 = ix ? b110 : b010;
            unsigned long long p11 = ix ? b111 : b011;
#pragma unroll
            for (int dy = -1; dy <= 1; dy++) {
                int ny = y + dy;
                if ((unsigned)ny >= SS) continue;
                int iy = (ny >> 2) - byl;
                unsigned long long q0 = iy ? p10 : p00;
                unsigned long long q1 = iy ? p11 : p01;
#pragma unroll
                for (int dz = -1; dz <= 1; dz++) {
                    int nz = z + dz;
                    if ((unsigned)nz >= SS) continue;
                    int iz = (nz >> 2) - bzl;
                    unsigned long long w = iz ? q1 : q0;
                    int bit = ((nx & 3) * 4 + (ny & 3)) * 4 + (nz & 3);
                    uint32_t h = (uint32_t)((w >> bit) & 1ull);
                    mask |= h << (((dx + 1) * 3 + (dy + 1)) * 3 + (dz + 1));
                }
            }
        }

        masks[i] = mask;
        uint32_t mm = mask;
        while (mm) {
            int k = __builtin_ctz(mm);
            mm &= mm - 1;
#pragma unroll
            for (int m = 0; m < CH; m++) o[m] += sW[k * CH + m];
        }
    }

    // wave butterfly reduce of sum & sumsq per channel, then one atomicAdd per block per slot
    int lane = t & 63, wid = t >> 6;
#pragma unroll
    for (int m = 0; m < CH; m++) {
        float v = o[m];
        float v2 = o[m] * o[m];
        for (int off = 32; off; off >>= 1) {
            v += __shfl_xor(v, off, 64);
            v2 += __shfl_xor(v2, off, 64);
        }
        if (lane == 0) { sred[wid][m] = v; sred[wid][16 + m] = v2; }
    }
    __syncthreads();
    if (t < 32) {
        float s = 0.f;
        int nw = blockDim.x >> 6;
        for (int w = 0; w < nw; w++) s += sred[w][t];
        atomicAdd(&sums[t], s);
    }
}

// ---------------- kernel 4: BN + ReLU + linear epilogue ----------------
__global__ void final_out(const uint32_t* __restrict__ masks, const float* __restrict__ W,
                          const float* __restrict__ sums, const float* __restrict__ gamma,
                          const float* __restrict__ beta, const float* __restrict__ lin_w,
                          const float* __restrict__ lin_b, float* __restrict__ out, int n) {
    __shared__ float sW[27 * CH];
    __shared__ float sA[CH], sB[CH], sLW[CH * NCLS], sLB[NCLS];
    int t = threadIdx.x;
    for (int j = t; j < 27 * CH; j += blockDim.x) sW[j] = W[j];
    if (t < CH) {
        float mean = sums[t] / (float)n;
        float var = sums[16 + t] / (float)n - mean * mean;
        float istd = rsqrtf(var + BN_EPS);
        float a = istd * gamma[t];
        sA[t] = a;
        sB[t] = beta[t] - mean * a;
    }
    if (t < CH * NCLS) sLW[t] = lin_w[t];
    if (t < NCLS) sLB[t] = lin_b[t];
    __syncthreads();

    int i = blockIdx.x * blockDim.x + t;
    if (i >= n) return;
    uint32_t mm = masks[i];
    float o[CH];
#pragma unroll
    for (int m = 0; m < CH; m++) o[m] = 0.f;
    while (mm) {
        int k = __builtin_ctz(mm);
        mm &= mm - 1;
#pragma unroll
        for (int m = 0; m < CH; m++) o[m] += sW[k * CH + m];
    }
    float res[NCLS];
#pragma unroll
    for (int c = 0; c < NCLS; c++) res[c] = sLB[c];
#pragma unroll
    for (int m = 0; m < CH; m++) {
        float h = fmaxf(o[m] * sA[m] + sB[m], 0.f);
#pragma unroll
        for (int c = 0; c < NCLS; c++) res[c] += h * sLW[m * NCLS + c];
    }
#pragma unroll
    for (int c = 0; c < NCLS; c++) out[(size_t)i * NCLS + c] = res[c];
}

extern "C" void kernel_launch(void* const* d_in, const int* in_sizes, int n_in,
                              void* d_out, int out_size, void* d_ws, size_t ws_size,
                              hipStream_t stream) {
    const float* pc    = (const float*)d_in[0];
    const float* W     = (const float*)d_in[1];
    const float* gamma = (const float*)d_in[2];
    const float* beta  = (const float*)d_in[3];
    const float* lin_w = (const float*)d_in[4];
    const float* lin_b = (const float*)d_in[5];
    float* out = (float*)d_out;

    int n = in_sizes[0] / 5;
    int nblk = (n + 255) / 256;

    // workspace layout: [sums 256B][fine 56.6MB][coarse 884KB][masks 8MB]
    char* ws = (char*)d_ws;
    float* sums = (float*)ws;
    unsigned long long* fine = (unsigned long long*)(ws + 256);
    char* coarse_base = ws + 256 + FINE_BYTES;
    uint32_t* coarse = (uint32_t*)coarse_base;
    unsigned long long* coarse64 = (unsigned long long*)coarse_base;
    uint32_t* masks = (uint32_t*)(coarse_base + COARSE_BYTES);
    size_t need = 256 + FINE_BYTES + COARSE_BYTES + (size_t)n * sizeof(uint32_t);
    if (ws_size < need) return;  // clean failure rather than OOB writes

    hipMemsetAsync(sums, 0, 256, stream);
    hipMemsetAsync(fine, 0, FINE_BYTES + COARSE_BYTES, stream);  // fine+coarse contiguous
    build_fine<<<nblk, 256, 0, stream>>>(pc, fine, n);
    build_coarse<<<(int)(FINE_WORDS / 256), 256, 0, stream>>>(fine, coarse64);
    mask_stats<<<nblk, 256, 0, stream>>>(pc, fine, coarse, W, masks, sums, n);
    final_out<<<nblk, 256, 0, stream>>>(masks, W, sums, gamma, beta, lin_w, lin_b, out, n);
}